// Round 10
// baseline (725.531 us; speedup 1.0000x reference)
//
#include <hip/hip_runtime.h>
#include <math.h>

#define NTOK 8192
#define KCODES 8192
#define DDIM 512
#define QELEMS (NTOK * DDIM)

// ---------------- fallback (round-6) chunking / offsets ---------------------
#define NCHUNK 8
#define CPC (KCODES / NCHUNK)   // 1024
#define LDK 40

constexpr size_t S_PART  = 0;
constexpr size_t S_XSQ   = 524288;
constexpr size_t S_CSQ   = S_XSQ + NTOK;
constexpr size_t S_LSE   = S_CSQ + KCODES;
constexpr size_t S_PLOGP = S_LSE + NTOK;
constexpr size_t S_D2    = S_PLOGP + NTOK;
constexpr size_t S_AVG   = S_D2 + NTOK;
constexpr size_t S_I1    = S_AVG + KCODES;
constexpr size_t S_I2    = S_I1 + NTOK;

// ---------------- fast-path chunking / offsets ------------------------------
#define NCHUNK_F 16
#define CPC_F (KCODES / NCHUNK_F)  // 512

constexpr size_t FS_PART  = 0;                        // 8192*16*8 = 1,048,576
constexpr size_t FS_XSQ   = 1048576;
constexpr size_t FS_CSQ   = FS_XSQ + NTOK;
constexpr size_t FS_LSE   = FS_CSQ + KCODES;
constexpr size_t FS_PLOGP = FS_LSE + NTOK;
constexpr size_t FS_D2    = FS_PLOGP + NTOK;
constexpr size_t FS_AVG   = FS_D2 + NTOK;
constexpr size_t FS_I1    = FS_AVG + KCODES;
constexpr size_t FS_I2    = FS_I1 + NTOK;

// ws layout (shorts): [0]=XH [1]=XL [2]=CBH [3]=CBL, each QELEMS shorts,
// tiled: idx(tile,kt,g,r,e) = ((tile*16+kt)*4+g)*1024 + r*8 + e
constexpr size_t WS_NEED_BYTES = 4ull * (size_t)QELEMS * 2ull;  // 33,554,432

typedef __attribute__((ext_vector_type(8))) short bf16x8;
typedef __attribute__((ext_vector_type(4))) float f32x4;

__device__ __forceinline__ bool better(float v, int i, float v2, int i2) {
  return v > v2 || (v == v2 && i < i2);
}

// fp32 -> (hi, lo) bf16 pair by truncation; hi+lo carries ~17 mantissa bits
__device__ __forceinline__ void cvt_hilo(float f, unsigned& h, unsigned& l) {
  const unsigned u = __float_as_uint(f);
  h = u >> 16;
  const float lf = f - __uint_as_float(u & 0xFFFF0000u);
  l = __float_as_uint(lf) >> 16;
}

__device__ __forceinline__ void gll16(const unsigned short* g, const short* l) {
  __builtin_amdgcn_global_load_lds(
      (const __attribute__((address_space(1))) unsigned int*)g,
      (__attribute__((address_space(3))) unsigned int*)l, 16, 0, 0);
}

// ---------------- squared norms (shared; offsets parameterized) -------------
__global__ __launch_bounds__(64) void sq_kernel(const float* __restrict__ x,
                                                const float* __restrict__ cb,
                                                float* __restrict__ dout,
                                                size_t offXsq, size_t offCsq) {
  const int row = blockIdx.x;  // 0..8191 codes, 8192..16383 tokens
  const int lane = threadIdx.x;
  const float* src = (row < KCODES) ? (cb + (size_t)row * DDIM)
                                    : (x + (size_t)(row - KCODES) * DDIM);
  float4 v0 = reinterpret_cast<const float4*>(src)[lane];
  float4 v1 = reinterpret_cast<const float4*>(src)[lane + 64];
  float s = v0.x*v0.x + v0.y*v0.y + v0.z*v0.z + v0.w*v0.w
          + v1.x*v1.x + v1.y*v1.y + v1.z*v1.z + v1.w*v1.w;
  #pragma unroll
  for (int o = 32; o; o >>= 1) s += __shfl_down(s, o);
  if (lane == 0) {
    if (row < KCODES) dout[offCsq + row] = s;
    else              dout[offXsq + (row - KCODES)] = s;
  }
}

__global__ void zero_kernel(float* __restrict__ dout, size_t offAvg) {
  dout[offAvg + blockIdx.x * 256 + threadIdx.x] = 0.f;
}

// ---------------- one-time fp32 -> tiled bf16 hi/lo conversion --------------
__global__ __launch_bounds__(256) void cvt_kernel(const float* __restrict__ x,
                                                  const float* __restrict__ cb,
                                                  unsigned short* __restrict__ ws) {
  const size_t fid = (size_t)blockIdx.x * 256 + threadIdx.x;  // float4 id
  const size_t half = (size_t)QELEMS / 4;                     // 1,048,576
  const bool isX = fid < half;
  const float* src = isX ? x : cb;
  unsigned short* dh = ws + (isX ? 0 : (size_t)2 * QELEMS);
  unsigned short* dl = dh + QELEMS;
  const size_t f = isX ? fid : fid - half;
  const size_t e0 = f * 4;
  const int row = (int)(e0 >> 9);
  const int k = (int)(e0 & 511);
  const int tile = row >> 7, r = row & 127;
  const int kt = k >> 5, gg = (k >> 3) & 3, e = k & 7;  // e in {0,4}
  const float4 v = *reinterpret_cast<const float4*>(src + e0);
  unsigned h0, h1, h2, h3, l0, l1, l2, l3;
  cvt_hilo(v.x, h0, l0); cvt_hilo(v.y, h1, l1);
  cvt_hilo(v.z, h2, l2); cvt_hilo(v.w, h3, l3);
  uint2 hp, lp;
  hp.x = h0 | (h1 << 16); hp.y = h2 | (h3 << 16);
  lp.x = l0 | (l1 << 16); lp.y = l2 | (l3 << 16);
  const size_t dst = (((size_t)tile * 16 + kt) * 4 + gg) * 1024 + (size_t)r * 8 + e;
  *reinterpret_cast<uint2*>(dh + dst) = hp;
  *reinterpret_cast<uint2*>(dl + dst) = lp;
}

// =========================================================================
// FAST PATH: pipelined global_load_lds staged MFMA GEMMs
//  - double-buffered LDS, one barrier per K-step (T3 minimal 2-phase)
//  - pass1: lane-local online softmax/top-2 state, merged once at kernel end
// =========================================================================

#define STAGE2(b_, s_)                                                        \
  {                                                                           \
    const int st_ = (s_) >> 4, kt_ = (s_) & 15;                               \
    const int tile_ = (w < 2) ? atile : ((chunk * CPC_F + st_ * 128) >> 7);   \
    const unsigned short* p = gb + (((size_t)tile_ * 16 + kt_) * 4096) + l * 8; \
    const short* lb = &lds4[b_][w][0];                                        \
    _Pragma("unroll")                                                         \
    for (int s8 = 0; s8 < 8; ++s8) gll16(p + s8 * 512, lb + s8 * 512);        \
  }

#define MFMA_KSTEP2(b_)                                                       \
  {                                                                           \
    const short* Lb = &lds4[b_][0][0];                                        \
    bf16x8 a_h[4], a_l[4];                                                    \
    _Pragma("unroll")                                                         \
    for (int fi = 0; fi < 4; ++fi) {                                          \
      const int ra = (wr * 64 + fi * 16 + lx) * 8 + kg * 1024;                \
      a_h[fi] = *reinterpret_cast<const bf16x8*>(Lb + ra);                    \
      a_l[fi] = *reinterpret_cast<const bf16x8*>(Lb + 4096 + ra);             \
    }                                                                         \
    _Pragma("unroll")                                                         \
    for (int fj = 0; fj < 4; ++fj) {                                          \
      const int rb = (wc * 64 + fj * 16 + lx) * 8 + kg * 1024;                \
      const bf16x8 b_h = *reinterpret_cast<const bf16x8*>(Lb + 8192 + rb);    \
      const bf16x8 b_l = *reinterpret_cast<const bf16x8*>(Lb + 12288 + rb);   \
      _Pragma("unroll")                                                       \
      for (int fi = 0; fi < 4; ++fi) {                                        \
        acc[fi][fj] = __builtin_amdgcn_mfma_f32_16x16x32_bf16(a_h[fi], b_h, acc[fi][fj], 0, 0, 0); \
        acc[fi][fj] = __builtin_amdgcn_mfma_f32_16x16x32_bf16(a_l[fi], b_h, acc[fi][fj], 0, 0, 0); \
        acc[fi][fj] = __builtin_amdgcn_mfma_f32_16x16x32_bf16(a_h[fi], b_l, acc[fi][fj], 0, 0, 0); \
      }                                                                       \
    }                                                                         \
  }

// ---------------- fast pass 1: GEMM + deferred lane-local row stats ---------
__global__ __launch_bounds__(256, 2) void pass1f(const unsigned short* __restrict__ ws,
                                                 float* __restrict__ dout) {
  __shared__ short lds4[2][4][4096];   // double-buffered {XH, XL, CBH, CBL}
  __shared__ float stats[2][128][6];   // final merge only
  const int tid = threadIdx.x;
  const int l = tid & 63;
  const int w = tid >> 6;
  const int wr = w >> 1, wc = w & 1;
  const int kg = l >> 4, lx = l & 15;
  const int m0 = blockIdx.y * 128;
  const int atile = blockIdx.y;
  const int chunk = blockIdx.x;

  float xs[16];
  #pragma unroll
  for (int fi = 0; fi < 4; ++fi)
    #pragma unroll
    for (int v = 0; v < 4; ++v)
      xs[fi * 4 + v] = dout[FS_XSQ + m0 + wr * 64 + fi * 16 + kg * 4 + v];

  // lane-local online state (v1 doubles as the softmax running max)
  float rv1[16], rv2[16], rz[16], rs[16];
  int ri1[16], ri2[16];
  #pragma unroll
  for (int r = 0; r < 16; ++r) {
    rv1[r] = -1e30f; rv2[r] = -1e30f; rz[r] = 0.f; rs[r] = 0.f;
    ri1[r] = 0x7fffffff; ri2[r] = 0x7fffffff;
  }

  const unsigned short* gb = ws + (size_t)w * (size_t)QELEMS;

  f32x4 acc[4][4];
  #pragma unroll
  for (int fi = 0; fi < 4; ++fi)
    #pragma unroll
    for (int fj = 0; fj < 4; ++fj)
      acc[fi][fj] = (f32x4){0.f, 0.f, 0.f, 0.f};

  STAGE2(0, 0);
  __syncthreads();

  for (int step = 0; step < 4 * 16; ++step) {
    const int cur = step & 1;
    if (step < 63) STAGE2(cur ^ 1, step + 1);
    MFMA_KSTEP2(cur);

    if ((step & 15) == 15) {
      const int st = step >> 4;
      const int n0 = chunk * CPC_F + st * 128;
      const int colbase = n0 + wc * 64 + lx;
      float cs[4];
      #pragma unroll
      for (int fj = 0; fj < 4; ++fj) cs[fj] = dout[FS_CSQ + colbase + fj * 16];

      #pragma unroll
      for (int fi = 0; fi < 4; ++fi) {
        #pragma unroll
        for (int v = 0; v < 4; ++v) {
          const int r = fi * 4 + v;
          const float xsv = xs[r];
          #pragma unroll
          for (int fj = 0; fj < 4; ++fj) {
            const float d2 = fmaxf(fmaf(-2.f, acc[fi][fj][v], xsv) + cs[fj], 0.f);
            const float f = -100.f * sqrtf(d2);
            const int c = colbase + fj * 16;
            if (f > rv1[r]) {
              const float a = __expf(rv1[r] - f);
              rs[r] = a * (rs[r] + (rv1[r] - f) * rz[r]);
              rz[r] = fmaf(a, rz[r], 1.0f);
              rv2[r] = rv1[r]; ri2[r] = ri1[r];
              rv1[r] = f; ri1[r] = c;
            } else {
              const float g = f - rv1[r];
              const float e = __expf(g);
              rz[r] += e;
              rs[r] = fmaf(e, g, rs[r]);
              if (better(f, c, rv2[r], ri2[r])) { rv2[r] = f; ri2[r] = c; }
            }
          }
        }
      }
      // reset accumulators for next st
      #pragma unroll
      for (int fi = 0; fi < 4; ++fi)
        #pragma unroll
        for (int fj = 0; fj < 4; ++fj)
          acc[fi][fj] = (f32x4){0.f, 0.f, 0.f, 0.f};
    }
    __syncthreads();
  }

  // -------- one-time cross-lane merge (16 lanes per row) --------
  #pragma unroll
  for (int r = 0; r < 16; ++r) {
    float v1 = rv1[r], v2 = rv2[r], z = rz[r], s = rs[r];
    int i1 = ri1[r], i2 = ri2[r];
    #pragma unroll
    for (int mask = 1; mask < 16; mask <<= 1) {
      const float ov1 = __shfl_xor(v1, mask);
      const float ov2 = __shfl_xor(v2, mask);
      const float oz  = __shfl_xor(z, mask);
      const float os  = __shfl_xor(s, mask);
      const int oi1 = __shfl_xor(i1, mask);
      const int oi2 = __shfl_xor(i2, mask);
      const float M = fmaxf(v1, ov1);
      const float ea = __expf(v1 - M), eb = __expf(ov1 - M);
      s = ea * (s + (v1 - M) * z) + eb * (os + (ov1 - M) * oz);
      z = ea * z + eb * oz;
      float n1, n2; int ni1, ni2;
      if (better(ov1, oi1, v1, i1)) {
        n1 = ov1; ni1 = oi1;
        if (better(v1, i1, ov2, oi2)) { n2 = v1; ni2 = i1; } else { n2 = ov2; ni2 = oi2; }
      } else {
        n1 = v1; ni1 = i1;
        if (better(ov1, oi1, v2, i2)) { n2 = ov1; ni2 = oi1; } else { n2 = v2; ni2 = i2; }
      }
      v1 = n1; i1 = ni1; v2 = n2; i2 = ni2;
    }
    if (lx == 0) {
      const int row = wr * 64 + (r >> 2) * 16 + kg * 4 + (r & 3);
      float* st_ = &stats[wc][row][0];
      st_[0] = v1; st_[1] = z; st_[2] = s; st_[3] = v2;
      st_[4] = __int_as_float(i1); st_[5] = __int_as_float(i2);
    }
  }

  __syncthreads();
  if (tid < 128) {
    float v1 = stats[0][tid][0], z = stats[0][tid][1], s = stats[0][tid][2], v2 = stats[0][tid][3];
    int i1 = __float_as_int(stats[0][tid][4]), i2 = __float_as_int(stats[0][tid][5]);
    const float ov1 = stats[1][tid][0], oz = stats[1][tid][1];
    const float os = stats[1][tid][2], ov2 = stats[1][tid][3];
    const int oi1 = __float_as_int(stats[1][tid][4]), oi2 = __float_as_int(stats[1][tid][5]);
    const float M = fmaxf(v1, ov1);
    const float ea = __expf(v1 - M), eb = __expf(ov1 - M);
    const float nz = ea * z + eb * oz;
    const float ns = ea * (s + (v1 - M) * z) + eb * (os + (ov1 - M) * oz);
    float n1, n2; int ni1, ni2;
    if (better(ov1, oi1, v1, i1)) {
      n1 = ov1; ni1 = oi1;
      if (better(v1, i1, ov2, oi2)) { n2 = v1; ni2 = i1; } else { n2 = ov2; ni2 = oi2; }
    } else {
      n1 = v1; ni1 = i1;
      if (better(ov1, oi1, v2, i2)) { n2 = ov1; ni2 = oi1; } else { n2 = v2; ni2 = i2; }
    }
    float* p = dout + FS_PART + ((size_t)(m0 + tid) * NCHUNK_F + chunk) * 8;
    p[0] = n1; p[1] = nz; p[2] = ns; p[3] = n2;
    p[4] = __int_as_float(ni1); p[5] = __int_as_float(ni2);
  }
}

// ---------------- fast pass 2: GEMM + avg_probs column sums -----------------
__global__ __launch_bounds__(256, 2) void colf(const unsigned short* __restrict__ ws,
                                               float* __restrict__ dout) {
  __shared__ short lds4[2][4][4096];
  __shared__ float red[4][64];
  const int tid = threadIdx.x;
  const int l = tid & 63;
  const int w = tid >> 6;
  const int wr = w >> 1, wc = w & 1;
  const int kg = l >> 4, lx = l & 15;
  const int m0 = blockIdx.y * 128;
  const int atile = blockIdx.y;
  const int chunk = blockIdx.x;

  float xs[16], lse[16];
  #pragma unroll
  for (int fi = 0; fi < 4; ++fi)
    #pragma unroll
    for (int v = 0; v < 4; ++v) {
      const int r = m0 + wr * 64 + fi * 16 + kg * 4 + v;
      xs[fi * 4 + v] = dout[FS_XSQ + r];
      lse[fi * 4 + v] = dout[FS_LSE + r];
    }

  const unsigned short* gb = ws + (size_t)w * (size_t)QELEMS;

  f32x4 acc[4][4];
  #pragma unroll
  for (int fi = 0; fi < 4; ++fi)
    #pragma unroll
    for (int fj = 0; fj < 4; ++fj)
      acc[fi][fj] = (f32x4){0.f, 0.f, 0.f, 0.f};

  STAGE2(0, 0);
  __syncthreads();

  for (int step = 0; step < 4 * 16; ++step) {
    const int cur = step & 1;
    if (step < 63) STAGE2(cur ^ 1, step + 1);
    MFMA_KSTEP2(cur);

    if ((step & 15) == 15) {
      const int st = step >> 4;
      const int n0 = chunk * CPC_F + st * 128;
      const int colbase = n0 + wc * 64 + lx;
      float cs[4];
      #pragma unroll
      for (int fj = 0; fj < 4; ++fj) cs[fj] = dout[FS_CSQ + colbase + fj * 16];

      float colsum[4] = {0.f, 0.f, 0.f, 0.f};
      #pragma unroll
      for (int fi = 0; fi < 4; ++fi) {
        #pragma unroll
        for (int v = 0; v < 4; ++v) {
          const float xsv = xs[fi * 4 + v];
          const float lsev = lse[fi * 4 + v];
          #pragma unroll
          for (int fj = 0; fj < 4; ++fj) {
            const float d2 = fmaxf(fmaf(-2.f, acc[fi][fj][v], xsv) + cs[fj], 0.f);
            const float f = -100.f * sqrtf(d2);
            colsum[fj] += __expf(f - lsev);
          }
        }
      }
      #pragma unroll
      for (int fj = 0; fj < 4; ++fj) {
        colsum[fj] += __shfl_xor(colsum[fj], 16);
        colsum[fj] += __shfl_xor(colsum[fj], 32);
      }
      __syncthreads();
      if (kg == 0) {
        #pragma unroll
        for (int fj = 0; fj < 4; ++fj) red[w][fj * 16 + lx] = colsum[fj];
      }
      __syncthreads();
      if (tid < 128) {
        const int wcc = tid >> 6, c = tid & 63;
        atomicAdd(&dout[FS_AVG + n0 + tid], red[wcc][c] + red[wcc + 2][c]);
      }
      // reset accumulators for next st
      #pragma unroll
      for (int fi = 0; fi < 4; ++fi)
        #pragma unroll
        for (int fj = 0; fj < 4; ++fj)
          acc[fi][fj] = (f32x4){0.f, 0.f, 0.f, 0.f};
    }
    __syncthreads();
  }
}

// =========================================================================
// FALLBACK (round-6 kernels, verbatim structure)
// =========================================================================

#define STAGE_TILES(kt_)                                                      \
  {                                                                           \
    const int kb = (kt_) * 32 + sc;                                           \
    _Pragma("unroll")                                                         \
    for (int rep = 0; rep < 4; ++rep) {                                       \
      const int row = sr + rep * 32;                                          \
      const float4 av = *reinterpret_cast<const float4*>(                     \
          x + (size_t)(m0 + row) * DDIM + kb);                                \
      const float4 bv = *reinterpret_cast<const float4*>(                     \
          cb + (size_t)(n0 + row) * DDIM + kb);                               \
      unsigned h0, h1, h2, h3, l0, l1, l2, l3;                                \
      uint2 t;                                                                \
      cvt_hilo(av.x, h0, l0); cvt_hilo(av.y, h1, l1);                         \
      cvt_hilo(av.z, h2, l2); cvt_hilo(av.w, h3, l3);                         \
      t.x = h0 | (h1 << 16); t.y = h2 | (h3 << 16);                           \
      *reinterpret_cast<uint2*>(&Ah[row][sc]) = t;                            \
      t.x = l0 | (l1 << 16); t.y = l2 | (l3 << 16);                           \
      *reinterpret_cast<uint2*>(&Al[row][sc]) = t;                            \
      cvt_hilo(bv.x, h0, l0); cvt_hilo(bv.y, h1, l1);                         \
      cvt_hilo(bv.z, h2, l2); cvt_hilo(bv.w, h3, l3);                         \
      t.x = h0 | (h1 << 16); t.y = h2 | (h3 << 16);                           \
      *reinterpret_cast<uint2*>(&Bh[row][sc]) = t;                            \
      t.x = l0 | (l1 << 16); t.y = l2 | (l3 << 16);                           \
      *reinterpret_cast<uint2*>(&Bl[row][sc]) = t;                            \
    }                                                                         \
  }

#define MFMA_KSTEP                                                            \
  {                                                                           \
    bf16x8 a_h[4], a_l[4];                                                    \
    _Pragma("unroll")                                                         \
    for (int fi = 0; fi < 4; ++fi) {                                          \
      a_h[fi] = *reinterpret_cast<const bf16x8*>(&Ah[ar + fi * 16][koff]);    \
      a_l[fi] = *reinterpret_cast<const bf16x8*>(&Al[ar + fi * 16][koff]);    \
    }                                                                         \
    _Pragma("unroll")                                                         \
    for (int fj = 0; fj < 4; ++fj) {                                          \
      const bf16x8 b_h = *reinterpret_cast<const bf16x8*>(&Bh[br + fj * 16][koff]); \
      const bf16x8 b_l = *reinterpret_cast<const bf16x8*>(&Bl[br + fj * 16][koff]); \
      _Pragma("unroll")                                                       \
      for (int fi = 0; fi < 4; ++fi) {                                        \
        acc[fi][fj] = __builtin_amdgcn_mfma_f32_16x16x32_bf16(a_h[fi], b_h, acc[fi][fj], 0, 0, 0); \
        acc[fi][fj] = __builtin_amdgcn_mfma_f32_16x16x32_bf16(a_l[fi], b_h, acc[fi][fj], 0, 0, 0); \
        acc[fi][fj] = __builtin_amdgcn_mfma_f32_16x16x32_bf16(a_h[fi], b_l, acc[fi][fj], 0, 0, 0); \
      }                                                                       \
    }                                                                         \
  }

__global__ __launch_bounds__(256) void pass1_mfma(const float* __restrict__ x,
                                                  const float* __restrict__ cb,
                                                  float* __restrict__ dout) {
  __shared__ short Ah[128][LDK], Al[128][LDK], Bh[128][LDK], Bl[128][LDK];
  __shared__ float stats[2][128][6];
  const int tid = threadIdx.x;
  const int l = tid & 63;
  const int w = tid >> 6;
  const int wr = w >> 1, wc = w & 1;
  const int g = l >> 4, lx = l & 15;
  const int ar = wr * 64 + lx;
  const int br = wc * 64 + lx;
  const int koff = g * 8;
  const int sr = tid >> 3;
  const int sc = (tid & 7) * 4;
  const int m0 = blockIdx.y * 128;
  const int chunk = blockIdx.x;

  if (tid < 128) {
    #pragma unroll
    for (int q = 0; q < 2; ++q) {
      stats[q][tid][0] = -1e30f; stats[q][tid][1] = 0.f; stats[q][tid][2] = 0.f;
      stats[q][tid][3] = -1e30f;
      stats[q][tid][4] = __int_as_float(0x7fffffff);
      stats[q][tid][5] = __int_as_float(0x7fffffff);
    }
  }

  float xs[16];
  #pragma unroll
  for (int fi = 0; fi < 4; ++fi)
    #pragma unroll
    for (int v = 0; v < 4; ++v)
      xs[fi * 4 + v] = dout[S_XSQ + m0 + wr * 64 + fi * 16 + g * 4 + v];

  for (int st = 0; st < CPC / 128; ++st) {
    const int n0 = chunk * CPC + st * 128;
    f32x4 acc[4][4];
    #pragma unroll
    for (int fi = 0; fi < 4; ++fi)
      #pragma unroll
      for (int fj = 0; fj < 4; ++fj)
        acc[fi][fj] = (f32x4){0.f, 0.f, 0.f, 0.f};

    for (int kt = 0; kt < DDIM / 32; ++kt) {
      __syncthreads();
      STAGE_TILES(kt);
      __syncthreads();
      MFMA_KSTEP;
    }

    const int colbase = n0 + wc * 64 + lx;
    float cs[4];
    #pragma unroll
    for (int fj = 0; fj < 4; ++fj) cs[fj] = dout[S_CSQ + colbase + fj * 16];

    #pragma unroll
    for (int fi = 0; fi < 4; ++fi) {
      #pragma unroll
      for (int v = 0; v < 4; ++v) {
        const float xsv = xs[fi * 4 + v];
        float fv[4];
        #pragma unroll
        for (int fj = 0; fj < 4; ++fj) {
          const float d2 = fmaxf(fmaf(-2.f, acc[fi][fj][v], xsv) + cs[fj], 0.f);
          fv[fj] = -100.f * sqrtf(d2);
        }
        float v1 = fv[0], v2 = -1e30f;
        int i1 = colbase, i2 = 0x7fffffff;
        #pragma unroll
        for (int fj = 1; fj < 4; ++fj) {
          const int c = colbase + fj * 16;
          if (better(fv[fj], c, v1, i1)) { v2 = v1; i2 = i1; v1 = fv[fj]; i1 = c; }
          else if (better(fv[fj], c, v2, i2)) { v2 = fv[fj]; i2 = c; }
        }
        #pragma unroll
        for (int mask = 1; mask < 16; mask <<= 1) {
          const float ov1 = __shfl_xor(v1, mask);
          const float ov2 = __shfl_xor(v2, mask);
          const int oi1 = __shfl_xor(i1, mask);
          const int oi2 = __shfl_xor(i2, mask);
          float n1, n2; int ni1, ni2;
          if (better(ov1, oi1, v1, i1)) {
            n1 = ov1; ni1 = oi1;
            if (better(v1, i1, ov2, oi2)) { n2 = v1; ni2 = i1; } else { n2 = ov2; ni2 = oi2; }
          } else {
            n1 = v1; ni1 = i1;
            if (better(ov1, oi1, v2, i2)) { n2 = ov1; ni2 = oi1; } else { n2 = v2; ni2 = i2; }
          }
          v1 = n1; i1 = ni1; v2 = n2; i2 = ni2;
        }
        float z = 0.f, s = 0.f;
        #pragma unroll
        for (int fj = 0; fj < 4; ++fj) {
          const float ge = fv[fj] - v1;
          const float e = __expf(ge);
          z += e; s = fmaf(e, ge, s);
        }
        #pragma unroll
        for (int mask = 1; mask < 16; mask <<= 1) {
          z += __shfl_xor(z, mask);
          s += __shfl_xor(s, mask);
        }
        if (lx == 0) {
          const int r = wr * 64 + fi * 16 + g * 4 + v;
          float* st_ = &stats[wc][r][0];
          const float ov1 = st_[0], oz = st_[1], os = st_[2], ov2 = st_[3];
          const int oi1 = __float_as_int(st_[4]), oi2 = __float_as_int(st_[5]);
          const float M = fmaxf(v1, ov1);
          const float ea = __expf(v1 - M), eb = __expf(ov1 - M);
          st_[1] = ea * z + eb * oz;
          st_[2] = ea * (s + (v1 - M) * z) + eb * (os + (ov1 - M) * oz);
          float n1, n2; int ni1, ni2;
          if (better(ov1, oi1, v1, i1)) {
            n1 = ov1; ni1 = oi1;
            if (better(v1, i1, ov2, oi2)) { n2 = v1; ni2 = i1; } else { n2 = ov2; ni2 = oi2; }
          } else {
            n1 = v1; ni1 = i1;
            if (better(ov1, oi1, v2, i2)) { n2 = ov1; ni2 = oi1; } else { n2 = v2; ni2 = i2; }
          }
          st_[0] = n1; st_[3] = n2;
          st_[4] = __int_as_float(ni1);
          st_[5] = __int_as_float(ni2);
        }
      }
    }
  }

  __syncthreads();
  if (tid < 128) {
    float v1 = stats[0][tid][0], z = stats[0][tid][1], s = stats[0][tid][2], v2 = stats[0][tid][3];
    int i1 = __float_as_int(stats[0][tid][4]), i2 = __float_as_int(stats[0][tid][5]);
    const float ov1 = stats[1][tid][0], oz = stats[1][tid][1];
    const float os = stats[1][tid][2], ov2 = stats[1][tid][3];
    const int oi1 = __float_as_int(stats[1][tid][4]), oi2 = __float_as_int(stats[1][tid][5]);
    const float M = fmaxf(v1, ov1);
    const float ea = __expf(v1 - M), eb = __expf(ov1 - M);
    const float nz = ea * z + eb * oz;
    const float ns = ea * (s + (v1 - M) * z) + eb * (os + (ov1 - M) * oz);
    float n1, n2; int ni1, ni2;
    if (better(ov1, oi1, v1, i1)) {
      n1 = ov1; ni1 = oi1;
      if (better(v1, i1, ov2, oi2)) { n2 = v1; ni2 = i1; } else { n2 = ov2; ni2 = oi2; }
    } else {
      n1 = v1; ni1 = i1;
      if (better(ov1, oi1, v2, i2)) { n2 = ov1; ni2 = oi1; } else { n2 = v2; ni2 = i2; }
    }
    float* p = dout + S_PART + ((size_t)(m0 + tid) * NCHUNK + chunk) * 8;
    p[0] = n1; p[1] = nz; p[2] = ns; p[3] = n2;
    p[4] = __int_as_float(ni1); p[5] = __int_as_float(ni2);
  }
}

__global__ __launch_bounds__(256) void col_mfma(const float* __restrict__ x,
                                                const float* __restrict__ cb,
                                                float* __restrict__ dout) {
  __shared__ short Ah[128][LDK], Al[128][LDK], Bh[128][LDK], Bl[128][LDK];
  __shared__ float red[4][64];
  const int tid = threadIdx.x;
  const int l = tid & 63;
  const int w = tid >> 6;
  const int wr = w >> 1, wc = w & 1;
  const int g = l >> 4, lx = l & 15;
  const int ar = wr * 64 + lx;
  const int br = wc * 64 + lx;
  const int koff = g * 8;
  const int sr = tid >> 3;
  const int sc = (tid & 7) * 4;
  const int m0 = blockIdx.y * 128;
  const int chunk = blockIdx.x;

  float xs[16], lse[16];
  #pragma unroll
  for (int fi = 0; fi < 4; ++fi)
    #pragma unroll
    for (int v = 0; v < 4; ++v) {
      const int r = m0 + wr * 64 + fi * 16 + g * 4 + v;
      xs[fi * 4 + v] = dout[S_XSQ + r];
      lse[fi * 4 + v] = dout[S_LSE + r];
    }

  for (int st = 0; st < CPC / 128; ++st) {
    const int n0 = chunk * CPC + st * 128;
    f32x4 acc[4][4];
    #pragma unroll
    for (int fi = 0; fi < 4; ++fi)
      #pragma unroll
      for (int fj = 0; fj < 4; ++fj)
        acc[fi][fj] = (f32x4){0.f, 0.f, 0.f, 0.f};

    for (int kt = 0; kt < DDIM / 32; ++kt) {
      __syncthreads();
      STAGE_TILES(kt);
      __syncthreads();
      MFMA_KSTEP;
    }

    const int colbase = n0 + wc * 64 + lx;
    float cs[4];
    #pragma unroll
    for (int fj = 0; fj < 4; ++fj) cs[fj] = dout[S_CSQ + colbase + fj * 16];

    float colsum[4] = {0.f, 0.f, 0.f, 0.f};
    #pragma unroll
    for (int fi = 0; fi < 4; ++fi) {
      #pragma unroll
      for (int v = 0; v < 4; ++v) {
        const float xsv = xs[fi * 4 + v];
        const float lsev = lse[fi * 4 + v];
        #pragma unroll
        for (int fj = 0; fj < 4; ++fj) {
          const float d2 = fmaxf(fmaf(-2.f, acc[fi][fj][v], xsv) + cs[fj], 0.f);
          const float f = -100.f * sqrtf(d2);
          colsum[fj] += __expf(f - lsev);
        }
      }
    }
    #pragma unroll
    for (int fj = 0; fj < 4; ++fj) {
      colsum[fj] += __shfl_xor(colsum[fj], 16);
      colsum[fj] += __shfl_xor(colsum[fj], 32);
    }
    __syncthreads();
    if (g == 0) {
      #pragma unroll
      for (int fj = 0; fj < 4; ++fj) red[w][fj * 16 + lx] = colsum[fj];
    }
    __syncthreads();
    if (tid < 128) {
      const int wcc = tid >> 6, c = tid & 63;
      atomicAdd(&dout[S_AVG + n0 + tid], red[wcc][c] + red[wcc + 2][c]);
    }
  }
}

// ---------------- shared small kernels (offset-parameterized) ---------------
__global__ __launch_bounds__(256) void merge_rows(float* __restrict__ dout,
                                                  size_t offPart, int nchunk,
                                                  size_t offLse, size_t offPlogp,
                                                  size_t offI1, size_t offI2) {
  const int t = blockIdx.x * 256 + threadIdx.x;
  float v1 = -1e30f, v2 = -1e30f, z = 0.f, s1 = 0.f;
  int i1 = 0x7fffffff, i2 = 0x7fffffff;
  for (int c = 0; c < nchunk; ++c) {
    const float* p = dout + offPart + ((size_t)t * nchunk + c) * 8;
    const float ov1 = p[0], oz = p[1], os1 = p[2], ov2 = p[3];
    const int oi1 = __float_as_int(p[4]), oi2 = __float_as_int(p[5]);
    const float M = fmaxf(v1, ov1);
    const float a = __expf(v1 - M);
    const float b = __expf(ov1 - M);
    s1 = a * (s1 + (v1 - M) * z) + b * (os1 + (ov1 - M) * oz);
    z  = a * z + b * oz;
    float n1, n2; int ni1, ni2;
    if (better(ov1, oi1, v1, i1)) {
      n1 = ov1; ni1 = oi1;
      if (better(v1, i1, ov2, oi2)) { n2 = v1; ni2 = i1; }
      else { n2 = ov2; ni2 = oi2; }
    } else {
      n1 = v1; ni1 = i1;
      if (better(ov1, oi1, v2, i2)) { n2 = ov1; ni2 = oi1; }
      else { n2 = v2; ni2 = i2; }
    }
    v1 = n1; i1 = ni1; v2 = n2; i2 = ni2;
  }
  const float lnZ = logf(z);
  dout[offLse + t] = v1 + lnZ;
  dout[offPlogp + t] = s1 / z - lnZ;
  reinterpret_cast<int*>(dout)[offI1 + t] = i1;
  reinterpret_cast<int*>(dout)[offI2 + t] = i2;
}

__global__ __launch_bounds__(64) void refine(const float* __restrict__ x,
                                             const float* __restrict__ cb,
                                             float* __restrict__ dout,
                                             size_t offI1, size_t offI2,
                                             size_t offD2) {
  const int t = blockIdx.x;
  const int lane = threadIdx.x;
  const int i1 = reinterpret_cast<const int*>(dout)[offI1 + t];
  const int i2 = reinterpret_cast<const int*>(dout)[offI2 + t];
  const float* xt = x + (size_t)t * DDIM;
  const float* c1 = cb + (size_t)i1 * DDIM;
  const float* c2 = cb + (size_t)i2 * DDIM;
  double d1 = 0.0, d2 = 0.0;
  #pragma unroll
  for (int j = 0; j < DDIM / 64; ++j) {
    const int d = j * 64 + lane;
    const double xv = (double)xt[d];
    const double u = xv - (double)c1[d];
    const double w = xv - (double)c2[d];
    d1 += u * u;
    d2 += w * w;
  }
  #pragma unroll
  for (int o = 32; o; o >>= 1) { d1 += __shfl_down(d1, o); d2 += __shfl_down(d2, o); }
  if (lane == 0) {
    const bool pick2 = (d2 < d1) || (d2 == d1 && i2 < i1);
    dout[offD2 + t] = (float)(pick2 ? d2 : d1);
    dout[(size_t)QELEMS + 4 + t] = (float)(pick2 ? i2 : i1);
  }
}

__global__ __launch_bounds__(256) void finalize(float* __restrict__ dout,
                                                size_t offAvg, size_t offPlogp,
                                                size_t offD2) {
  const int tid = threadIdx.x;
  float ent = 0.f, sp = 0.f, sd = 0.f;
  for (int j = 0; j < KCODES / 256; ++j) {
    const float a = dout[offAvg + j * 256 + tid] * (1.0f / (float)NTOK);
    ent -= a * logf(a + 1e-8f);
    sp += dout[offPlogp + j * 256 + tid];
    sd += dout[offD2 + j * 256 + tid];
  }
  __shared__ float se[256], sP[256], sD[256];
  se[tid] = ent; sP[tid] = sp; sD[tid] = sd;
  __syncthreads();
  for (int s = 128; s > 0; s >>= 1) {
    if (tid < s) { se[tid] += se[tid + s]; sP[tid] += sP[tid + s]; sD[tid] += sD[tid + s]; }
    __syncthreads();
  }
  if (tid == 0) {
    const float avg_entropy = se[0];
    const float sample_entropy = -sP[0] / (float)NTOK;
    const float entropy_loss = (sample_entropy - avg_entropy) * 0.1f;
    const float mse = sD[0] / (float)QELEMS;
    const float commit = 0.5f * mse * 0.25f;
    const float cbl = 0.5f * mse;
    dout[QELEMS + 0] = cbl + commit + entropy_loss;
    dout[QELEMS + 1] = commit;
    dout[QELEMS + 2] = cbl;
    dout[QELEMS + 3] = entropy_loss;
  }
}

__global__ __launch_bounds__(128) void gather_kernel(const float* __restrict__ x,
                                                     const float* __restrict__ cb,
                                                     float* __restrict__ dout) {
  const int t = blockIdx.x;
  const int tid = threadIdx.x;
  const int idx = (int)dout[(size_t)QELEMS + 4 + t];
  const float4 cv = reinterpret_cast<const float4*>(cb + (size_t)idx * DDIM)[tid];
  reinterpret_cast<float4*>(dout + (size_t)t * DDIM)[tid] = cv;
}

extern "C" void kernel_launch(void* const* d_in, const int* in_sizes, int n_in,
                              void* d_out, int out_size, void* d_ws, size_t ws_size,
                              hipStream_t stream) {
  const float* x = (const float*)d_in[0];    // (4,2048,512)
  const float* cb = (const float*)d_in[1];   // (8192,512)
  float* dout = (float*)d_out;

  if (ws_size >= WS_NEED_BYTES) {
    unsigned short* ws = (unsigned short*)d_ws;
    sq_kernel<<<KCODES + NTOK, 64, 0, stream>>>(x, cb, dout, FS_XSQ, FS_CSQ);
    zero_kernel<<<KCODES / 256, 256, 0, stream>>>(dout, FS_AVG);
    cvt_kernel<<<2 * QELEMS / 4 / 256, 256, 0, stream>>>(x, cb, ws);
    pass1f<<<dim3(NCHUNK_F, NTOK / 128), 256, 0, stream>>>(ws, dout);
    merge_rows<<<NTOK / 256, 256, 0, stream>>>(dout, FS_PART, NCHUNK_F,
                                               FS_LSE, FS_PLOGP, FS_I1, FS_I2);
    refine<<<NTOK, 64, 0, stream>>>(x, cb, dout, FS_I1, FS_I2, FS_D2);
    colf<<<dim3(NCHUNK_F, NTOK / 128), 256, 0, stream>>>(ws, dout);
    finalize<<<1, 256, 0, stream>>>(dout, FS_AVG, FS_PLOGP, FS_D2);
    gather_kernel<<<NTOK, 128, 0, stream>>>(x, cb, dout);
  } else {
    sq_kernel<<<KCODES + NTOK, 64, 0, stream>>>(x, cb, dout, S_XSQ, S_CSQ);
    zero_kernel<<<KCODES / 256, 256, 0, stream>>>(dout, S_AVG);
    pass1_mfma<<<dim3(NCHUNK, NTOK / 128), 256, 0, stream>>>(x, cb, dout);
    merge_rows<<<NTOK / 256, 256, 0, stream>>>(dout, S_PART, NCHUNK,
                                               S_LSE, S_PLOGP, S_I1, S_I2);
    refine<<<NTOK, 64, 0, stream>>>(x, cb, dout, S_I1, S_I2, S_D2);
    col_mfma<<<dim3(NCHUNK, NTOK / 128), 256, 0, stream>>>(x, cb, dout);
    finalize<<<1, 256, 0, stream>>>(dout, S_AVG, S_PLOGP, S_D2);
    gather_kernel<<<NTOK, 128, 0, stream>>>(x, cb, dout);
  }
}

// Round 11
// 576.215 us; speedup vs baseline: 1.2591x; 1.2591x over previous
//
#include <hip/hip_runtime.h>
#include <math.h>

#define NTOK 8192
#define KCODES 8192
#define DDIM 512
#define QELEMS (NTOK * DDIM)

// ---------------- fallback (round-6) chunking / offsets ---------------------
#define NCHUNK 8
#define CPC (KCODES / NCHUNK)   // 1024
#define LDK 40

constexpr size_t S_PART  = 0;
constexpr size_t S_XSQ   = 524288;
constexpr size_t S_CSQ   = S_XSQ + NTOK;
constexpr size_t S_LSE   = S_CSQ + KCODES;
constexpr size_t S_PLOGP = S_LSE + NTOK;
constexpr size_t S_D2    = S_PLOGP + NTOK;
constexpr size_t S_AVG   = S_D2 + NTOK;
constexpr size_t S_I1    = S_AVG + KCODES;
constexpr size_t S_I2    = S_I1 + NTOK;

// ---------------- fast-path chunking / offsets ------------------------------
#define NCHUNK_F 16
#define CPC_F (KCODES / NCHUNK_F)  // 512

constexpr size_t FS_PART  = 0;                        // 8192*16*8 = 1,048,576
constexpr size_t FS_XSQ   = 1048576;
constexpr size_t FS_CSQ   = FS_XSQ + NTOK;
constexpr size_t FS_LSE   = FS_CSQ + KCODES;
constexpr size_t FS_PLOGP = FS_LSE + NTOK;
constexpr size_t FS_D2    = FS_PLOGP + NTOK;
constexpr size_t FS_AVG   = FS_D2 + NTOK;
constexpr size_t FS_I1    = FS_AVG + KCODES;
constexpr size_t FS_I2    = FS_I1 + NTOK;

// ws layout (shorts): [0]=XH [1]=XL [2]=CBH [3]=CBL, each QELEMS shorts,
// tiled: idx(tile,kt,g,r,e) = ((tile*16+kt)*4+g)*1024 + r*8 + e
constexpr size_t WS_NEED_BYTES = 4ull * (size_t)QELEMS * 2ull;  // 33,554,432

typedef __attribute__((ext_vector_type(8))) short bf16x8;
typedef __attribute__((ext_vector_type(4))) float f32x4;

__device__ __forceinline__ bool better(float v, int i, float v2, int i2) {
  return v > v2 || (v == v2 && i < i2);
}

// fp32 -> (hi, lo) bf16 pair by truncation; hi+lo carries ~17 mantissa bits
__device__ __forceinline__ void cvt_hilo(float f, unsigned& h, unsigned& l) {
  const unsigned u = __float_as_uint(f);
  h = u >> 16;
  const float lf = f - __uint_as_float(u & 0xFFFF0000u);
  l = __float_as_uint(lf) >> 16;
}

__device__ __forceinline__ void gll16(const unsigned short* g, const short* l) {
  __builtin_amdgcn_global_load_lds(
      (const __attribute__((address_space(1))) unsigned int*)g,
      (__attribute__((address_space(3))) unsigned int*)l, 16, 0, 0);
}

// ---------------- squared norms (shared; offsets parameterized) -------------
__global__ __launch_bounds__(64) void sq_kernel(const float* __restrict__ x,
                                                const float* __restrict__ cb,
                                                float* __restrict__ dout,
                                                size_t offXsq, size_t offCsq) {
  const int row = blockIdx.x;  // 0..8191 codes, 8192..16383 tokens
  const int lane = threadIdx.x;
  const float* src = (row < KCODES) ? (cb + (size_t)row * DDIM)
                                    : (x + (size_t)(row - KCODES) * DDIM);
  float4 v0 = reinterpret_cast<const float4*>(src)[lane];
  float4 v1 = reinterpret_cast<const float4*>(src)[lane + 64];
  float s = v0.x*v0.x + v0.y*v0.y + v0.z*v0.z + v0.w*v0.w
          + v1.x*v1.x + v1.y*v1.y + v1.z*v1.z + v1.w*v1.w;
  #pragma unroll
  for (int o = 32; o; o >>= 1) s += __shfl_down(s, o);
  if (lane == 0) {
    if (row < KCODES) dout[offCsq + row] = s;
    else              dout[offXsq + (row - KCODES)] = s;
  }
}

__global__ void zero_kernel(float* __restrict__ dout, size_t offAvg) {
  dout[offAvg + blockIdx.x * 256 + threadIdx.x] = 0.f;
}

// ---------------- one-time fp32 -> tiled bf16 hi/lo conversion --------------
__global__ __launch_bounds__(256) void cvt_kernel(const float* __restrict__ x,
                                                  const float* __restrict__ cb,
                                                  unsigned short* __restrict__ ws) {
  const size_t fid = (size_t)blockIdx.x * 256 + threadIdx.x;  // float4 id
  const size_t half = (size_t)QELEMS / 4;                     // 1,048,576
  const bool isX = fid < half;
  const float* src = isX ? x : cb;
  unsigned short* dh = ws + (isX ? 0 : (size_t)2 * QELEMS);
  unsigned short* dl = dh + QELEMS;
  const size_t f = isX ? fid : fid - half;
  const size_t e0 = f * 4;
  const int row = (int)(e0 >> 9);
  const int k = (int)(e0 & 511);
  const int tile = row >> 7, r = row & 127;
  const int kt = k >> 5, gg = (k >> 3) & 3, e = k & 7;  // e in {0,4}
  const float4 v = *reinterpret_cast<const float4*>(src + e0);
  unsigned h0, h1, h2, h3, l0, l1, l2, l3;
  cvt_hilo(v.x, h0, l0); cvt_hilo(v.y, h1, l1);
  cvt_hilo(v.z, h2, l2); cvt_hilo(v.w, h3, l3);
  uint2 hp, lp;
  hp.x = h0 | (h1 << 16); hp.y = h2 | (h3 << 16);
  lp.x = l0 | (l1 << 16); lp.y = l2 | (l3 << 16);
  const size_t dst = (((size_t)tile * 16 + kt) * 4 + gg) * 1024 + (size_t)r * 8 + e;
  *reinterpret_cast<uint2*>(dh + dst) = hp;
  *reinterpret_cast<uint2*>(dl + dst) = lp;
}

// =========================================================================
// FAST PATH: statically double-buffered global_load_lds MFMA GEMMs
//  - two distinct __shared__ arrays -> compiler can prove load/read disjoint
//  - pass1: full hi/lo precision, round-7 per-st epilogue (low VGPR)
//  - colf:  hi-only GEMM (softmax near-one-hot; avg_probs tolerates ~1%)
// =========================================================================

#define STAGE_P1(dst_, s_)                                                    \
  {                                                                           \
    const int st_ = (s_) >> 4, kt_ = (s_) & 15;                               \
    const int tile_ = (w < 2) ? atile : ((chunk * CPC_F + st_ * 128) >> 7);   \
    const unsigned short* p = gb + (((size_t)tile_ * 16 + kt_) * 4096) + l * 8; \
    const short* lb = &dst_[w][0];                                            \
    _Pragma("unroll")                                                         \
    for (int s8 = 0; s8 < 8; ++s8) gll16(p + s8 * 512, lb + s8 * 512);        \
  }

#define MFMA_P1(src_)                                                         \
  {                                                                           \
    bf16x8 a_h[4], a_l[4];                                                    \
    _Pragma("unroll")                                                         \
    for (int fi = 0; fi < 4; ++fi) {                                          \
      const int ra = (wr * 64 + fi * 16 + lx) * 8 + kg * 1024;                \
      a_h[fi] = *reinterpret_cast<const bf16x8*>(&src_[0][ra]);               \
      a_l[fi] = *reinterpret_cast<const bf16x8*>(&src_[1][ra]);               \
    }                                                                         \
    _Pragma("unroll")                                                         \
    for (int fj = 0; fj < 4; ++fj) {                                          \
      const int rb = (wc * 64 + fj * 16 + lx) * 8 + kg * 1024;                \
      const bf16x8 b_h = *reinterpret_cast<const bf16x8*>(&src_[2][rb]);      \
      const bf16x8 b_l = *reinterpret_cast<const bf16x8*>(&src_[3][rb]);      \
      _Pragma("unroll")                                                       \
      for (int fi = 0; fi < 4; ++fi) {                                        \
        acc[fi][fj] = __builtin_amdgcn_mfma_f32_16x16x32_bf16(a_h[fi], b_h, acc[fi][fj], 0, 0, 0); \
        acc[fi][fj] = __builtin_amdgcn_mfma_f32_16x16x32_bf16(a_l[fi], b_h, acc[fi][fj], 0, 0, 0); \
        acc[fi][fj] = __builtin_amdgcn_mfma_f32_16x16x32_bf16(a_h[fi], b_l, acc[fi][fj], 0, 0, 0); \
      }                                                                       \
    }                                                                         \
  }

// round-7 per-st epilogue: online row softmax stats + top-2, merged in LDS
#define EPI_P1(st_)                                                           \
  {                                                                           \
    const int n0 = chunk * CPC_F + (st_) * 128;                               \
    const int colbase = n0 + wc * 64 + lx;                                    \
    float cs[4];                                                              \
    _Pragma("unroll")                                                         \
    for (int fj = 0; fj < 4; ++fj) cs[fj] = dout[FS_CSQ + colbase + fj * 16]; \
    _Pragma("unroll")                                                         \
    for (int fi = 0; fi < 4; ++fi) {                                          \
      _Pragma("unroll")                                                       \
      for (int v = 0; v < 4; ++v) {                                           \
        const float xsv = xs[fi * 4 + v];                                     \
        float fv[4];                                                          \
        _Pragma("unroll")                                                     \
        for (int fj = 0; fj < 4; ++fj) {                                      \
          const float d2 = fmaxf(fmaf(-2.f, acc[fi][fj][v], xsv) + cs[fj], 0.f); \
          fv[fj] = -100.f * sqrtf(d2);                                        \
        }                                                                     \
        float v1 = fv[0], v2 = -1e30f;                                        \
        int i1 = colbase, i2 = 0x7fffffff;                                    \
        _Pragma("unroll")                                                     \
        for (int fj = 1; fj < 4; ++fj) {                                      \
          const int c = colbase + fj * 16;                                    \
          if (better(fv[fj], c, v1, i1)) { v2 = v1; i2 = i1; v1 = fv[fj]; i1 = c; } \
          else if (better(fv[fj], c, v2, i2)) { v2 = fv[fj]; i2 = c; }        \
        }                                                                     \
        _Pragma("unroll")                                                     \
        for (int mask = 1; mask < 16; mask <<= 1) {                           \
          const float ov1 = __shfl_xor(v1, mask);                             \
          const float ov2 = __shfl_xor(v2, mask);                             \
          const int oi1 = __shfl_xor(i1, mask);                               \
          const int oi2 = __shfl_xor(i2, mask);                               \
          float n1, n2; int ni1, ni2;                                         \
          if (better(ov1, oi1, v1, i1)) {                                     \
            n1 = ov1; ni1 = oi1;                                              \
            if (better(v1, i1, ov2, oi2)) { n2 = v1; ni2 = i1; } else { n2 = ov2; ni2 = oi2; } \
          } else {                                                            \
            n1 = v1; ni1 = i1;                                                \
            if (better(ov1, oi1, v2, i2)) { n2 = ov1; ni2 = oi1; } else { n2 = v2; ni2 = i2; } \
          }                                                                   \
          v1 = n1; i1 = ni1; v2 = n2; i2 = ni2;                               \
        }                                                                     \
        float z = 0.f, s = 0.f;                                               \
        _Pragma("unroll")                                                     \
        for (int fj = 0; fj < 4; ++fj) {                                      \
          const float ge = fv[fj] - v1;                                       \
          const float e = __expf(ge);                                         \
          z += e; s = fmaf(e, ge, s);                                         \
        }                                                                     \
        _Pragma("unroll")                                                     \
        for (int mask = 1; mask < 16; mask <<= 1) {                           \
          z += __shfl_xor(z, mask);                                           \
          s += __shfl_xor(s, mask);                                           \
        }                                                                     \
        if (lx == 0) {                                                        \
          const int r = wr * 64 + fi * 16 + kg * 4 + v;                       \
          float* st2 = &stats[wc][r][0];                                      \
          const float ov1 = st2[0], oz = st2[1], os = st2[2], ov2 = st2[3];   \
          const int oi1 = __float_as_int(st2[4]), oi2 = __float_as_int(st2[5]); \
          const float M = fmaxf(v1, ov1);                                     \
          const float ea = __expf(v1 - M), eb = __expf(ov1 - M);              \
          st2[1] = ea * z + eb * oz;                                          \
          st2[2] = ea * (s + (v1 - M) * z) + eb * (os + (ov1 - M) * oz);      \
          float n1, n2; int ni1, ni2;                                         \
          if (better(ov1, oi1, v1, i1)) {                                     \
            n1 = ov1; ni1 = oi1;                                              \
            if (better(v1, i1, ov2, oi2)) { n2 = v1; ni2 = i1; } else { n2 = ov2; ni2 = oi2; } \
          } else {                                                            \
            n1 = v1; ni1 = i1;                                                \
            if (better(ov1, oi1, v2, i2)) { n2 = ov1; ni2 = oi1; } else { n2 = v2; ni2 = i2; } \
          }                                                                   \
          st2[0] = n1; st2[3] = n2;                                           \
          st2[4] = __int_as_float(ni1);                                       \
          st2[5] = __int_as_float(ni2);                                       \
        }                                                                     \
      }                                                                       \
    }                                                                         \
    _Pragma("unroll")                                                         \
    for (int fi = 0; fi < 4; ++fi)                                            \
      _Pragma("unroll")                                                       \
      for (int fj = 0; fj < 4; ++fj)                                          \
        acc[fi][fj] = (f32x4){0.f, 0.f, 0.f, 0.f};                            \
  }

// ---------------- fast pass 1: full-precision GEMM + fused row stats --------
__global__ __launch_bounds__(256, 2) void pass1f(const unsigned short* __restrict__ ws,
                                                 float* __restrict__ dout) {
  __shared__ short ldsA[4][4096];     // buffer A: {XH, XL, CBH, CBL}
  __shared__ short ldsB[4][4096];     // buffer B
  __shared__ float stats[2][128][6];  // [wc][row]{m, z, s1, v2, i1, i2}
  const int tid = threadIdx.x;
  const int l = tid & 63;
  const int w = tid >> 6;
  const int wr = w >> 1, wc = w & 1;
  const int kg = l >> 4, lx = l & 15;
  const int m0 = blockIdx.y * 128;
  const int atile = blockIdx.y;
  const int chunk = blockIdx.x;

  if (tid < 128) {
    #pragma unroll
    for (int q = 0; q < 2; ++q) {
      stats[q][tid][0] = -1e30f; stats[q][tid][1] = 0.f; stats[q][tid][2] = 0.f;
      stats[q][tid][3] = -1e30f;
      stats[q][tid][4] = __int_as_float(0x7fffffff);
      stats[q][tid][5] = __int_as_float(0x7fffffff);
    }
  }

  float xs[16];
  #pragma unroll
  for (int fi = 0; fi < 4; ++fi)
    #pragma unroll
    for (int v = 0; v < 4; ++v)
      xs[fi * 4 + v] = dout[FS_XSQ + m0 + wr * 64 + fi * 16 + kg * 4 + v];

  const unsigned short* gb = ws + (size_t)w * (size_t)QELEMS;

  f32x4 acc[4][4];
  #pragma unroll
  for (int fi = 0; fi < 4; ++fi)
    #pragma unroll
    for (int fj = 0; fj < 4; ++fj)
      acc[fi][fj] = (f32x4){0.f, 0.f, 0.f, 0.f};

  STAGE_P1(ldsA, 0);
  __syncthreads();

  for (int i = 0; i < 32; ++i) {
    const int so = 2 * i + 1;
    STAGE_P1(ldsB, so);
    MFMA_P1(ldsA);
    __syncthreads();
    if (so < 63) STAGE_P1(ldsA, so + 1);
    MFMA_P1(ldsB);
    if ((so & 15) == 15) EPI_P1(so >> 4);
    __syncthreads();
  }

  if (tid < 128) {
    float v1 = stats[0][tid][0], z = stats[0][tid][1], s = stats[0][tid][2], v2 = stats[0][tid][3];
    int i1 = __float_as_int(stats[0][tid][4]), i2 = __float_as_int(stats[0][tid][5]);
    const float ov1 = stats[1][tid][0], oz = stats[1][tid][1];
    const float os = stats[1][tid][2], ov2 = stats[1][tid][3];
    const int oi1 = __float_as_int(stats[1][tid][4]), oi2 = __float_as_int(stats[1][tid][5]);
    const float M = fmaxf(v1, ov1);
    const float ea = __expf(v1 - M), eb = __expf(ov1 - M);
    const float nz = ea * z + eb * oz;
    const float ns = ea * (s + (v1 - M) * z) + eb * (os + (ov1 - M) * oz);
    float n1, n2; int ni1, ni2;
    if (better(ov1, oi1, v1, i1)) {
      n1 = ov1; ni1 = oi1;
      if (better(v1, i1, ov2, oi2)) { n2 = v1; ni2 = i1; } else { n2 = ov2; ni2 = oi2; }
    } else {
      n1 = v1; ni1 = i1;
      if (better(ov1, oi1, v2, i2)) { n2 = ov1; ni2 = oi1; } else { n2 = v2; ni2 = i2; }
    }
    float* p = dout + FS_PART + ((size_t)(m0 + tid) * NCHUNK_F + chunk) * 8;
    p[0] = n1; p[1] = nz; p[2] = ns; p[3] = n2;
    p[4] = __int_as_float(ni1); p[5] = __int_as_float(ni2);
  }
}

// ---------------- fast pass 2: hi-only GEMM + avg_probs column sums ---------
#define STAGE_CF(dst_, s_)                                                    \
  {                                                                           \
    const int st_ = (s_) >> 4, kt_ = (s_) & 15;                               \
    const int tile_ = (w < 2) ? atile : ((chunk * CPC_F + st_ * 128) >> 7);   \
    const unsigned short* base = ws + ((w < 2) ? (size_t)0 : (size_t)2 * QELEMS); \
    const unsigned short* p = base + (((size_t)tile_ * 16 + kt_) * 4096)      \
                              + (size_t)(w & 1) * 2048 + l * 8;               \
    const short* lb = &dst_[w >> 1][(w & 1) * 2048];                          \
    _Pragma("unroll")                                                         \
    for (int s8 = 0; s8 < 4; ++s8) gll16(p + s8 * 512, lb + s8 * 512);        \
  }

#define MFMA_CF(src_)                                                         \
  {                                                                           \
    bf16x8 a_h[4];                                                            \
    _Pragma("unroll")                                                         \
    for (int fi = 0; fi < 4; ++fi) {                                          \
      const int ra = (wr * 64 + fi * 16 + lx) * 8 + kg * 1024;                \
      a_h[fi] = *reinterpret_cast<const bf16x8*>(&src_[0][ra]);               \
    }                                                                         \
    _Pragma("unroll")                                                         \
    for (int fj = 0; fj < 4; ++fj) {                                          \
      const int rb = (wc * 64 + fj * 16 + lx) * 8 + kg * 1024;                \
      const bf16x8 b_h = *reinterpret_cast<const bf16x8*>(&src_[1][rb]);      \
      _Pragma("unroll")                                                       \
      for (int fi = 0; fi < 4; ++fi)                                          \
        acc[fi][fj] = __builtin_amdgcn_mfma_f32_16x16x32_bf16(a_h[fi], b_h, acc[fi][fj], 0, 0, 0); \
    }                                                                         \
  }

#define EPI_CF(st_)                                                           \
  {                                                                           \
    const int n0 = chunk * CPC_F + (st_) * 128;                               \
    const int colbase = n0 + wc * 64 + lx;                                    \
    float cs[4];                                                              \
    _Pragma("unroll")                                                         \
    for (int fj = 0; fj < 4; ++fj) cs[fj] = dout[FS_CSQ + colbase + fj * 16]; \
    float colsum[4] = {0.f, 0.f, 0.f, 0.f};                                   \
    _Pragma("unroll")                                                         \
    for (int fi = 0; fi < 4; ++fi) {                                          \
      _Pragma("unroll")                                                       \
      for (int v = 0; v < 4; ++v) {                                           \
        const float xsv = xs[fi * 4 + v];                                     \
        const float lsev = lse[fi * 4 + v];                                   \
        _Pragma("unroll")                                                     \
        for (int fj = 0; fj < 4; ++fj) {                                      \
          const float d2 = fmaxf(fmaf(-2.f, acc[fi][fj][v], xsv) + cs[fj], 0.f); \
          const float f = -100.f * sqrtf(d2);                                 \
          colsum[fj] += __expf(f - lsev);                                     \
        }                                                                     \
      }                                                                       \
    }                                                                         \
    _Pragma("unroll")                                                         \
    for (int fj = 0; fj < 4; ++fj) {                                          \
      colsum[fj] += __shfl_xor(colsum[fj], 16);                               \
      colsum[fj] += __shfl_xor(colsum[fj], 32);                               \
    }                                                                         \
    __syncthreads();                                                          \
    if (kg == 0) {                                                            \
      _Pragma("unroll")                                                       \
      for (int fj = 0; fj < 4; ++fj) red[w][fj * 16 + lx] = colsum[fj];       \
    }                                                                         \
    __syncthreads();                                                          \
    if (tid < 128) {                                                          \
      const int wcc = tid >> 6, c = tid & 63;                                 \
      atomicAdd(&dout[FS_AVG + n0 + tid], red[wcc][c] + red[wcc + 2][c]);     \
    }                                                                         \
    _Pragma("unroll")                                                         \
    for (int fi = 0; fi < 4; ++fi)                                            \
      _Pragma("unroll")                                                       \
      for (int fj = 0; fj < 4; ++fj)                                          \
        acc[fi][fj] = (f32x4){0.f, 0.f, 0.f, 0.f};                            \
  }

__global__ __launch_bounds__(256, 4) void colf(const unsigned short* __restrict__ ws,
                                               float* __restrict__ dout) {
  __shared__ short ldsHA[2][4096];   // buffer A: {XH, CBH}
  __shared__ short ldsHB[2][4096];   // buffer B
  __shared__ float red[4][64];
  const int tid = threadIdx.x;
  const int l = tid & 63;
  const int w = tid >> 6;
  const int wr = w >> 1, wc = w & 1;
  const int kg = l >> 4, lx = l & 15;
  const int m0 = blockIdx.y * 128;
  const int atile = blockIdx.y;
  const int chunk = blockIdx.x;

  float xs[16], lse[16];
  #pragma unroll
  for (int fi = 0; fi < 4; ++fi)
    #pragma unroll
    for (int v = 0; v < 4; ++v) {
      const int r = m0 + wr * 64 + fi * 16 + kg * 4 + v;
      xs[fi * 4 + v] = dout[FS_XSQ + r];
      lse[fi * 4 + v] = dout[FS_LSE + r];
    }

  f32x4 acc[4][4];
  #pragma unroll
  for (int fi = 0; fi < 4; ++fi)
    #pragma unroll
    for (int fj = 0; fj < 4; ++fj)
      acc[fi][fj] = (f32x4){0.f, 0.f, 0.f, 0.f};

  STAGE_CF(ldsHA, 0);
  __syncthreads();

  for (int i = 0; i < 32; ++i) {
    const int so = 2 * i + 1;
    STAGE_CF(ldsHB, so);
    MFMA_CF(ldsHA);
    __syncthreads();
    if (so < 63) STAGE_CF(ldsHA, so + 1);
    MFMA_CF(ldsHB);
    if ((so & 15) == 15) EPI_CF(so >> 4);
    __syncthreads();
  }
}

// =========================================================================
// FALLBACK (round-6 kernels, verbatim structure)
// =========================================================================

#define STAGE_TILES(kt_)                                                      \
  {                                                                           \
    const int kb = (kt_) * 32 + sc;                                           \
    _Pragma("unroll")                                                         \
    for (int rep = 0; rep < 4; ++rep) {                                       \
      const int row = sr + rep * 32;                                          \
      const float4 av = *reinterpret_cast<const float4*>(                     \
          x + (size_t)(m0 + row) * DDIM + kb);                                \
      const float4 bv = *reinterpret_cast<const float4*>(                     \
          cb + (size_t)(n0 + row) * DDIM + kb);                               \
      unsigned h0, h1, h2, h3, l0, l1, l2, l3;                                \
      uint2 t;                                                                \
      cvt_hilo(av.x, h0, l0); cvt_hilo(av.y, h1, l1);                         \
      cvt_hilo(av.z, h2, l2); cvt_hilo(av.w, h3, l3);                         \
      t.x = h0 | (h1 << 16); t.y = h2 | (h3 << 16);                           \
      *reinterpret_cast<uint2*>(&Ah[row][sc]) = t;                            \
      t.x = l0 | (l1 << 16); t.y = l2 | (l3 << 16);                           \
      *reinterpret_cast<uint2*>(&Al[row][sc]) = t;                            \
      cvt_hilo(bv.x, h0, l0); cvt_hilo(bv.y, h1, l1);                         \
      cvt_hilo(bv.z, h2, l2); cvt_hilo(bv.w, h3, l3);                         \
      t.x = h0 | (h1 << 16); t.y = h2 | (h3 << 16);                           \
      *reinterpret_cast<uint2*>(&Bh[row][sc]) = t;                            \
      t.x = l0 | (l1 << 16); t.y = l2 | (l3 << 16);                           \
      *reinterpret_cast<uint2*>(&Bl[row][sc]) = t;                            \
    }                                                                         \
  }

#define MFMA_KSTEP                                                            \
  {                                                                           \
    bf16x8 a_h[4], a_l[4];                                                    \
    _Pragma("unroll")                                                         \
    for (int fi = 0; fi < 4; ++fi) {                                          \
      a_h[fi] = *reinterpret_cast<const bf16x8*>(&Ah[ar + fi * 16][koff]);    \
      a_l[fi] = *reinterpret_cast<const bf16x8*>(&Al[ar + fi * 16][koff]);    \
    }                                                                         \
    _Pragma("unroll")                                                         \
    for (int fj = 0; fj < 4; ++fj) {                                          \
      const bf16x8 b_h = *reinterpret_cast<const bf16x8*>(&Bh[br + fj * 16][koff]); \
      const bf16x8 b_l = *reinterpret_cast<const bf16x8*>(&Bl[br + fj * 16][koff]); \
      _Pragma("unroll")                                                       \
      for (int fi = 0; fi < 4; ++fi) {                                        \
        acc[fi][fj] = __builtin_amdgcn_mfma_f32_16x16x32_bf16(a_h[fi], b_h, acc[fi][fj], 0, 0, 0); \
        acc[fi][fj] = __builtin_amdgcn_mfma_f32_16x16x32_bf16(a_l[fi], b_h, acc[fi][fj], 0, 0, 0); \
        acc[fi][fj] = __builtin_amdgcn_mfma_f32_16x16x32_bf16(a_h[fi], b_l, acc[fi][fj], 0, 0, 0); \
      }                                                                       \
    }                                                                         \
  }

__global__ __launch_bounds__(256) void pass1_mfma(const float* __restrict__ x,
                                                  const float* __restrict__ cb,
                                                  float* __restrict__ dout) {
  __shared__ short Ah[128][LDK], Al[128][LDK], Bh[128][LDK], Bl[128][LDK];
  __shared__ float stats[2][128][6];
  const int tid = threadIdx.x;
  const int l = tid & 63;
  const int w = tid >> 6;
  const int wr = w >> 1, wc = w & 1;
  const int g = l >> 4, lx = l & 15;
  const int ar = wr * 64 + lx;
  const int br = wc * 64 + lx;
  const int koff = g * 8;
  const int sr = tid >> 3;
  const int sc = (tid & 7) * 4;
  const int m0 = blockIdx.y * 128;
  const int chunk = blockIdx.x;

  if (tid < 128) {
    #pragma unroll
    for (int q = 0; q < 2; ++q) {
      stats[q][tid][0] = -1e30f; stats[q][tid][1] = 0.f; stats[q][tid][2] = 0.f;
      stats[q][tid][3] = -1e30f;
      stats[q][tid][4] = __int_as_float(0x7fffffff);
      stats[q][tid][5] = __int_as_float(0x7fffffff);
    }
  }

  float xs[16];
  #pragma unroll
  for (int fi = 0; fi < 4; ++fi)
    #pragma unroll
    for (int v = 0; v < 4; ++v)
      xs[fi * 4 + v] = dout[S_XSQ + m0 + wr * 64 + fi * 16 + g * 4 + v];

  for (int st = 0; st < CPC / 128; ++st) {
    const int n0 = chunk * CPC + st * 128;
    f32x4 acc[4][4];
    #pragma unroll
    for (int fi = 0; fi < 4; ++fi)
      #pragma unroll
      for (int fj = 0; fj < 4; ++fj)
        acc[fi][fj] = (f32x4){0.f, 0.f, 0.f, 0.f};

    for (int kt = 0; kt < DDIM / 32; ++kt) {
      __syncthreads();
      STAGE_TILES(kt);
      __syncthreads();
      MFMA_KSTEP;
    }

    const int colbase = n0 + wc * 64 + lx;
    float cs[4];
    #pragma unroll
    for (int fj = 0; fj < 4; ++fj) cs[fj] = dout[S_CSQ + colbase + fj * 16];

    #pragma unroll
    for (int fi = 0; fi < 4; ++fi) {
      #pragma unroll
      for (int v = 0; v < 4; ++v) {
        const float xsv = xs[fi * 4 + v];
        float fv[4];
        #pragma unroll
        for (int fj = 0; fj < 4; ++fj) {
          const float d2 = fmaxf(fmaf(-2.f, acc[fi][fj][v], xsv) + cs[fj], 0.f);
          fv[fj] = -100.f * sqrtf(d2);
        }
        float v1 = fv[0], v2 = -1e30f;
        int i1 = colbase, i2 = 0x7fffffff;
        #pragma unroll
        for (int fj = 1; fj < 4; ++fj) {
          const int c = colbase + fj * 16;
          if (better(fv[fj], c, v1, i1)) { v2 = v1; i2 = i1; v1 = fv[fj]; i1 = c; }
          else if (better(fv[fj], c, v2, i2)) { v2 = fv[fj]; i2 = c; }
        }
        #pragma unroll
        for (int mask = 1; mask < 16; mask <<= 1) {
          const float ov1 = __shfl_xor(v1, mask);
          const float ov2 = __shfl_xor(v2, mask);
          const int oi1 = __shfl_xor(i1, mask);
          const int oi2 = __shfl_xor(i2, mask);
          float n1, n2; int ni1, ni2;
          if (better(ov1, oi1, v1, i1)) {
            n1 = ov1; ni1 = oi1;
            if (better(v1, i1, ov2, oi2)) { n2 = v1; ni2 = i1; } else { n2 = ov2; ni2 = oi2; }
          } else {
            n1 = v1; ni1 = i1;
            if (better(ov1, oi1, v2, i2)) { n2 = ov1; ni2 = oi1; } else { n2 = v2; ni2 = i2; }
          }
          v1 = n1; i1 = ni1; v2 = n2; i2 = ni2;
        }
        float z = 0.f, s = 0.f;
        #pragma unroll
        for (int fj = 0; fj < 4; ++fj) {
          const float ge = fv[fj] - v1;
          const float e = __expf(ge);
          z += e; s = fmaf(e, ge, s);
        }
        #pragma unroll
        for (int mask = 1; mask < 16; mask <<= 1) {
          z += __shfl_xor(z, mask);
          s += __shfl_xor(s, mask);
        }
        if (lx == 0) {
          const int r = wr * 64 + fi * 16 + g * 4 + v;
          float* st_ = &stats[wc][r][0];
          const float ov1 = st_[0], oz = st_[1], os = st_[2], ov2 = st_[3];
          const int oi1 = __float_as_int(st_[4]), oi2 = __float_as_int(st_[5]);
          const float M = fmaxf(v1, ov1);
          const float ea = __expf(v1 - M), eb = __expf(ov1 - M);
          st_[1] = ea * z + eb * oz;
          st_[2] = ea * (s + (v1 - M) * z) + eb * (os + (ov1 - M) * oz);
          float n1, n2; int ni1, ni2;
          if (better(ov1, oi1, v1, i1)) {
            n1 = ov1; ni1 = oi1;
            if (better(v1, i1, ov2, oi2)) { n2 = v1; ni2 = i1; } else { n2 = ov2; ni2 = oi2; }
          } else {
            n1 = v1; ni1 = i1;
            if (better(ov1, oi1, v2, i2)) { n2 = ov1; ni2 = oi1; } else { n2 = v2; ni2 = i2; }
          }
          st_[0] = n1; st_[3] = n2;
          st_[4] = __int_as_float(ni1);
          st_[5] = __int_as_float(ni2);
        }
      }
    }
  }

  __syncthreads();
  if (tid < 128) {
    float v1 = stats[0][tid][0], z = stats[0][tid][1], s = stats[0][tid][2], v2 = stats[0][tid][3];
    int i1 = __float_as_int(stats[0][tid][4]), i2 = __float_as_int(stats[0][tid][5]);
    const float ov1 = stats[1][tid][0], oz = stats[1][tid][1];
    const float os = stats[1][tid][2], ov2 = stats[1][tid][3];
    const int oi1 = __float_as_int(stats[1][tid][4]), oi2 = __float_as_int(stats[1][tid][5]);
    const float M = fmaxf(v1, ov1);
    const float ea = __expf(v1 - M), eb = __expf(ov1 - M);
    const float nz = ea * z + eb * oz;
    const float ns = ea * (s + (v1 - M) * z) + eb * (os + (ov1 - M) * oz);
    float n1, n2; int ni1, ni2;
    if (better(ov1, oi1, v1, i1)) {
      n1 = ov1; ni1 = oi1;
      if (better(v1, i1, ov2, oi2)) { n2 = v1; ni2 = i1; } else { n2 = ov2; ni2 = oi2; }
    } else {
      n1 = v1; ni1 = i1;
      if (better(ov1, oi1, v2, i2)) { n2 = ov1; ni2 = oi1; } else { n2 = v2; ni2 = i2; }
    }
    float* p = dout + S_PART + ((size_t)(m0 + tid) * NCHUNK + chunk) * 8;
    p[0] = n1; p[1] = nz; p[2] = ns; p[3] = n2;
    p[4] = __int_as_float(ni1); p[5] = __int_as_float(ni2);
  }
}

__global__ __launch_bounds__(256) void col_mfma(const float* __restrict__ x,
                                                const float* __restrict__ cb,
                                                float* __restrict__ dout) {
  __shared__ short Ah[128][LDK], Al[128][LDK], Bh[128][LDK], Bl[128][LDK];
  __shared__ float red[4][64];
  const int tid = threadIdx.x;
  const int l = tid & 63;
  const int w = tid >> 6;
  const int wr = w >> 1, wc = w & 1;
  const int g = l >> 4, lx = l & 15;
  const int ar = wr * 64 + lx;
  const int br = wc * 64 + lx;
  const int koff = g * 8;
  const int sr = tid >> 3;
  const int sc = (tid & 7) * 4;
  const int m0 = blockIdx.y * 128;
  const int chunk = blockIdx.x;

  float xs[16], lse[16];
  #pragma unroll
  for (int fi = 0; fi < 4; ++fi)
    #pragma unroll
    for (int v = 0; v < 4; ++v) {
      const int r = m0 + wr * 64 + fi * 16 + g * 4 + v;
      xs[fi * 4 + v] = dout[S_XSQ + r];
      lse[fi * 4 + v] = dout[S_LSE + r];
    }

  for (int st = 0; st < CPC / 128; ++st) {
    const int n0 = chunk * CPC + st * 128;
    f32x4 acc[4][4];
    #pragma unroll
    for (int fi = 0; fi < 4; ++fi)
      #pragma unroll
      for (int fj = 0; fj < 4; ++fj)
        acc[fi][fj] = (f32x4){0.f, 0.f, 0.f, 0.f};

    for (int kt = 0; kt < DDIM / 32; ++kt) {
      __syncthreads();
      STAGE_TILES(kt);
      __syncthreads();
      MFMA_KSTEP;
    }

    const int colbase = n0 + wc * 64 + lx;
    float cs[4];
    #pragma unroll
    for (int fj = 0; fj < 4; ++fj) cs[fj] = dout[S_CSQ + colbase + fj * 16];

    float colsum[4] = {0.f, 0.f, 0.f, 0.f};
    #pragma unroll
    for (int fi = 0; fi < 4; ++fi) {
      #pragma unroll
      for (int v = 0; v < 4; ++v) {
        const float xsv = xs[fi * 4 + v];
        const float lsev = lse[fi * 4 + v];
        #pragma unroll
        for (int fj = 0; fj < 4; ++fj) {
          const float d2 = fmaxf(fmaf(-2.f, acc[fi][fj][v], xsv) + cs[fj], 0.f);
          const float f = -100.f * sqrtf(d2);
          colsum[fj] += __expf(f - lsev);
        }
      }
    }
    #pragma unroll
    for (int fj = 0; fj < 4; ++fj) {
      colsum[fj] += __shfl_xor(colsum[fj], 16);
      colsum[fj] += __shfl_xor(colsum[fj], 32);
    }
    __syncthreads();
    if (g == 0) {
      #pragma unroll
      for (int fj = 0; fj < 4; ++fj) red[w][fj * 16 + lx] = colsum[fj];
    }
    __syncthreads();
    if (tid < 128) {
      const int wcc = tid >> 6, c = tid & 63;
      atomicAdd(&dout[S_AVG + n0 + tid], red[wcc][c] + red[wcc + 2][c]);
    }
  }
}

// ---------------- shared small kernels (offset-parameterized) ---------------
__global__ __launch_bounds__(256) void merge_rows(float* __restrict__ dout,
                                                  size_t offPart, int nchunk,
                                                  size_t offLse, size_t offPlogp,
                                                  size_t offI1, size_t offI2) {
  const int t = blockIdx.x * 256 + threadIdx.x;
  float v1 = -1e30f, v2 = -1e30f, z = 0.f, s1 = 0.f;
  int i1 = 0x7fffffff, i2 = 0x7fffffff;
  for (int c = 0; c < nchunk; ++c) {
    const float* p = dout + offPart + ((size_t)t * nchunk + c) * 8;
    const float ov1 = p[0], oz = p[1], os1 = p[2], ov2 = p[3];
    const int oi1 = __float_as_int(p[4]), oi2 = __float_as_int(p[5]);
    const float M = fmaxf(v1, ov1);
    const float a = __expf(v1 - M);
    const float b = __expf(ov1 - M);
    s1 = a * (s1 + (v1 - M) * z) + b * (os1 + (ov1 - M) * oz);
    z  = a * z + b * oz;
    float n1, n2; int ni1, ni2;
    if (better(ov1, oi1, v1, i1)) {
      n1 = ov1; ni1 = oi1;
      if (better(v1, i1, ov2, oi2)) { n2 = v1; ni2 = i1; }
      else { n2 = ov2; ni2 = oi2; }
    } else {
      n1 = v1; ni1 = i1;
      if (better(ov1, oi1, v2, i2)) { n2 = ov1; ni2 = oi1; }
      else { n2 = v2; ni2 = i2; }
    }
    v1 = n1; i1 = ni1; v2 = n2; i2 = ni2;
  }
  const float lnZ = logf(z);
  dout[offLse + t] = v1 + lnZ;
  dout[offPlogp + t] = s1 / z - lnZ;
  reinterpret_cast<int*>(dout)[offI1 + t] = i1;
  reinterpret_cast<int*>(dout)[offI2 + t] = i2;
}

__global__ __launch_bounds__(64) void refine(const float* __restrict__ x,
                                             const float* __restrict__ cb,
                                             float* __restrict__ dout,
                                             size_t offI1, size_t offI2,
                                             size_t offD2) {
  const int t = blockIdx.x;
  const int lane = threadIdx.x;
  const int i1 = reinterpret_cast<const int*>(dout)[offI1 + t];
  const int i2 = reinterpret_cast<const int*>(dout)[offI2 + t];
  const float* xt = x + (size_t)t * DDIM;
  const float* c1 = cb + (size_t)i1 * DDIM;
  const float* c2 = cb + (size_t)i2 * DDIM;
  double d1 = 0.0, d2 = 0.0;
  #pragma unroll
  for (int j = 0; j < DDIM / 64; ++j) {
    const int d = j * 64 + lane;
    const double xv = (double)xt[d];
    const double u = xv - (double)c1[d];
    const double w = xv - (double)c2[d];
    d1 += u * u;
    d2 += w * w;
  }
  #pragma unroll
  for (int o = 32; o; o >>= 1) { d1 += __shfl_down(d1, o); d2 += __shfl_down(d2, o); }
  if (lane == 0) {
    const bool pick2 = (d2 < d1) || (d2 == d1 && i2 < i1);
    dout[offD2 + t] = (float)(pick2 ? d2 : d1);
    dout[(size_t)QELEMS + 4 + t] = (float)(pick2 ? i2 : i1);
  }
}

__global__ __launch_bounds__(256) void finalize(float* __restrict__ dout,
                                                size_t offAvg, size_t offPlogp,
                                                size_t offD2) {
  const int tid = threadIdx.x;
  float ent = 0.f, sp = 0.f, sd = 0.f;
  for (int j = 0; j < KCODES / 256; ++j) {
    const float a = dout[offAvg + j * 256 + tid] * (1.0f / (float)NTOK);
    ent -= a * logf(a + 1e-8f);
    sp += dout[offPlogp + j * 256 + tid];
    sd += dout[offD2 + j * 256 + tid];
  }
  __shared__ float se[256], sP[256], sD[256];
  se[tid] = ent; sP[tid] = sp; sD[tid] = sd;
  __syncthreads();
  for (int s = 128; s > 0; s >>= 1) {
    if (tid < s) { se[tid] += se[tid + s]; sP[tid] += sP[tid + s]; sD[tid] += sD[tid + s]; }
    __syncthreads();
  }
  if (tid == 0) {
    const float avg_entropy = se[0];
    const float sample_entropy = -sP[0] / (float)NTOK;
    const float entropy_loss = (sample_entropy - avg_entropy) * 0.1f;
    const float mse = sD[0] / (float)QELEMS;
    const float commit = 0.5f * mse * 0.25f;
    const float cbl = 0.5f * mse;
    dout[QELEMS + 0] = cbl + commit + entropy_loss;
    dout[QELEMS + 1] = commit;
    dout[QELEMS + 2] = cbl;
    dout[QELEMS + 3] = entropy_loss;
  }
}

__global__ __launch_bounds__(128) void gather_kernel(const float* __restrict__ x,
                                                     const float* __restrict__ cb,
                                                     float* __restrict__ dout) {
  const int t = blockIdx.x;
  const int tid = threadIdx.x;
  const int idx = (int)dout[(size_t)QELEMS + 4 + t];
  const float4 cv = reinterpret_cast<const float4*>(cb + (size_t)idx * DDIM)[tid];
  reinterpret_cast<float4*>(dout + (size_t)t * DDIM)[tid] = cv;
}

extern "C" void kernel_launch(void* const* d_in, const int* in_sizes, int n_in,
                              void* d_out, int out_size, void* d_ws, size_t ws_size,
                              hipStream_t stream) {
  const float* x = (const float*)d_in[0];    // (4,2048,512)
  const float* cb = (const float*)d_in[1];   // (8192,512)
  float* dout = (float*)d_out;

  if (ws_size >= WS_NEED_BYTES) {
    unsigned short* ws = (unsigned short*)d_ws;
    sq_kernel<<<KCODES + NTOK, 64, 0, stream>>>(x, cb, dout, FS_XSQ, FS_CSQ);
    zero_kernel<<<KCODES / 256, 256, 0, stream>>>(dout, FS_AVG);
    cvt_kernel<<<2 * QELEMS / 4 / 256, 256, 0, stream>>>(x, cb, ws);
    pass1f<<<dim3(NCHUNK_F, NTOK / 128), 256, 0, stream>>>(ws, dout);
    merge_rows<<<NTOK / 256, 256, 0, stream>>>(dout, FS_PART, NCHUNK_F,
                                               FS_LSE, FS_PLOGP, FS_I1, FS_I2);
    refine<<<NTOK, 64, 0, stream>>>(x, cb, dout, FS_I1, FS_I2, FS_D2);
    colf<<<dim3(NCHUNK_F, NTOK / 128), 256, 0, stream>>>(ws, dout);
    finalize<<<1, 256, 0, stream>>>(dout, FS_AVG, FS_PLOGP, FS_D2);
    gather_kernel<<<NTOK, 128, 0, stream>>>(x, cb, dout);
  } else {
    sq_kernel<<<KCODES + NTOK, 64, 0, stream>>>(x, cb, dout, S_XSQ, S_CSQ);
    zero_kernel<<<KCODES / 256, 256, 0, stream>>>(dout, S_AVG);
    pass1_mfma<<<dim3(NCHUNK, NTOK / 128), 256, 0, stream>>>(x, cb, dout);
    merge_rows<<<NTOK / 256, 256, 0, stream>>>(dout, S_PART, NCHUNK,
                                               S_LSE, S_PLOGP, S_I1, S_I2);
    refine<<<NTOK, 64, 0, stream>>>(x, cb, dout, S_I1, S_I2, S_D2);
    col_mfma<<<dim3(NCHUNK, NTOK / 128), 256, 0, stream>>>(x, cb, dout);
    finalize<<<1, 256, 0, stream>>>(dout, S_AVG, S_PLOGP, S_D2);
    gather_kernel<<<NTOK, 128, 0, stream>>>(x, cb, dout);
  }
}